// Round 12
// baseline (210.167 us; speedup 1.0000x reference)
//
#include <hip/hip_runtime.h>

// Problem constants
#define T_SEQ 2048
#define C_DIM 1024
#define H_NUM 16
#define H_D   64
#define B_NUM 4
#define M_ROWS 8192   // B*T

typedef __attribute__((ext_vector_type(4))) float f32x4;
typedef __attribute__((ext_vector_type(8))) short bf16x8;   // 8 bf16 = 4 VGPRs (per guide §3)

__device__ __forceinline__ unsigned short f2bf(float f) {
  union { float f; unsigned int u; } a;
  a.f = f;
  unsigned int u = a.u;
  u += 0x7fffu + ((u >> 16) & 1u);   // RNE
  return (unsigned short)(u >> 16);
}

__device__ __forceinline__ unsigned int fbits(float f) {
  union { float f; unsigned int u; } a; a.f = f; return a.u;
}

// pack the high halves (bf16-truncate) of two f32 into one u32: {hi(b), hi(a)}
__device__ __forceinline__ unsigned int pack_hi(float a, float b) {
#if __has_builtin(__builtin_amdgcn_perm)
  return __builtin_amdgcn_perm(fbits(b), fbits(a), 0x07060302u);  // 1 VALU op
#else
  return (fbits(b) & 0xffff0000u) | (fbits(a) >> 16);
#endif
}

// async global->LDS, 16B per lane; LDS dest = wave-uniform base + lane*16
__device__ __forceinline__ void gload_lds16(const unsigned short* g, unsigned short* l) {
  __builtin_amdgcn_global_load_lds(
      (const __attribute__((address_space(1))) unsigned int*)g,
      (__attribute__((address_space(3))) unsigned int*)l, 16, 0, 0);
}

// ---------------------------------------------------------------- fused cast fp32 -> bf16
__global__ __launch_bounds__(256) void cast_all_kernel(const float* __restrict__ x,
                                                       const float* __restrict__ wa,
                                                       const float* __restrict__ wp,
                                                       unsigned short* __restrict__ xb,
                                                       unsigned short* __restrict__ wab,
                                                       unsigned short* __restrict__ wpb) {
  int i = blockIdx.x * 256 + threadIdx.x;
  const float* src;
  unsigned short* dst;
  int off;
  if (i < 2097152) {           // x: 8192*1024/4
    src = x; dst = xb; off = i;
  } else if (i < 2883584) {    // w_attn: 3072*1024/4
    src = wa; dst = wab; off = i - 2097152;
  } else {                     // w_proj: 1024*1024/4
    src = wp; dst = wpb; off = i - 2883584;
  }
  float4 v = reinterpret_cast<const float4*>(src)[off];
  ushort4 o;
  o.x = f2bf(v.x); o.y = f2bf(v.y); o.z = f2bf(v.z); o.w = f2bf(v.w);
  reinterpret_cast<ushort4*>(dst)[off] = o;
}

// ---------------------------------------------------------------- GEMM  C = A * B^T
// Round 12: the unexplored TLP cell. r8 reproduced (90.5us, MfmaUtil 23%) but
// aggregate staging = 17.6 B/cy/CU vs m97's measured 23.2 on the SAME
// structure -> the per-CU rate ceiling is NOT yet reached at 4 blk/CU; the
// per-block rate has been flat (~4.4) from 2->4 blocks. The 4-block cap was
// a register artifact, and smaller tiles relax registers faster than the
// per-wave cap shrinks:
//   EPI0: BN=64 @ launch_bounds(256,6) -> 6 blk/CU. acc[4][2]=32 AGPR +
//   ~52 arch VGPR ~ 84 <= 512/6 = 85 cap. LDS 24KB x 6 = 144 <= 160.
//   Grid 64x48 = 3072 = EXACTLY 2 rounds of 1536 resident. Law: I=42.7,
//   rate min(6x4.4, 23.2) -> 608-692 TF vs r8's 563.
//   EPI1: unchanged r8 config (BN=128, grid 512, (256,4)).
// Template/swizzle/epilogue identical to the verified kernel (parameter-only
// change; BN=64 path ran refcheck-correct as r3/r4's EPI1).
// EPI 0: QKV epilogue -> q*0.125*log2e, k [BH,T,D], v^T [BH,D,T'] k-permuted
// EPI 1: plain fp32 row-major [M,1024] output
template <int EPI>
__global__ __launch_bounds__(256, (EPI == 0) ? 6 : 4) void gemm_bt_kernel(
    const unsigned short* __restrict__ A,
    const unsigned short* __restrict__ Bw,
    unsigned short* __restrict__ q_ws,
    unsigned short* __restrict__ k_ws,
    unsigned short* __restrict__ v_ws,
    float* __restrict__ outf) {
  constexpr int BN  = (EPI == 0) ? 64 : 128;
  constexpr int NN  = (EPI == 0) ? 3072 : 1024;
  constexpr int NBC = NN / BN;           // 48 or 8
  constexpr int NFR = BN / 32;           // n-frags per wave: 2 or 4
  constexpr int BLD = BN * 8 / 256;      // B staging chunks per thread: 2 or 4
  constexpr int KK  = 1024;
  constexpr int KT  = KK / 64;           // 16
  constexpr int NWG = 64 * NBC;          // 3072 or 512 (both % 8 == 0)

  __shared__ unsigned short lds[8192 + BN * 64];   // A 16KB | B 8KB/16KB

  // T1: bijective XCD-aware swizzle (NWG % 8 == 0)
  const int bid = blockIdx.x;
  const int logical = (bid & 7) * (NWG / 8) + (bid >> 3);
  const int rb = logical / NBC, cb = logical % NBC;

  const int t = threadIdx.x;
  const int w = t >> 6, l = t & 63;
  const int wr = w >> 1, wc = w & 1;
  const int lq = l & 15, lg = l >> 4;

  const size_t a_base = (size_t)(rb * 128) * KK;
  const size_t b_base = (size_t)(cb * BN) * KK;

  // staging chunk c = t + 256*i -> (row=c>>3, slot=c&7), src slot ^= row&7
  int aRow[4], aGs[4];
#pragma unroll
  for (int i = 0; i < 4; ++i) {
    int c = t + 256 * i;
    aRow[i] = c >> 3;
    aGs[i] = (c & 7) ^ (aRow[i] & 7);
  }
  int bRow[BLD], bGs[BLD];
#pragma unroll
  for (int i = 0; i < BLD; ++i) {
    int c = t + 256 * i;
    bRow[i] = c >> 3;
    bGs[i] = (c & 7) ^ (bRow[i] & 7);
  }

  f32x4 acc[4][NFR] = {};

  for (int kt = 0; kt < KT; ++kt) {
    const int ko = kt * 64;
#pragma unroll
    for (int i = 0; i < 4; ++i)
      gload_lds16(A + a_base + (size_t)aRow[i] * KK + ko + aGs[i] * 8,
                  &lds[(t + 256 * i) * 8]);
#pragma unroll
    for (int i = 0; i < BLD; ++i)
      gload_lds16(Bw + b_base + (size_t)bRow[i] * KK + ko + bGs[i] * 8,
                  &lds[8192 + (t + 256 * i) * 8]);
    __syncthreads();   // drains vmcnt -> tile kt fully in LDS

#pragma unroll
    for (int kk = 0; kk < 2; ++kk) {
      const int sg = kk * 4 + lg;
      bf16x8 af[4], bfv[NFR];
#pragma unroll
      for (int i = 0; i < 4; ++i) {
        int R = wr * 64 + i * 16 + lq;
        af[i] = *reinterpret_cast<const bf16x8*>(&lds[(R * 8 + (sg ^ (R & 7))) * 8]);
      }
#pragma unroll
      for (int j = 0; j < NFR; ++j) {
        int R = wc * (BN / 2) + j * 16 + lq;
        bfv[j] = *reinterpret_cast<const bf16x8*>(&lds[8192 + (R * 8 + (sg ^ (R & 7))) * 8]);
      }
#pragma unroll
      for (int i = 0; i < 4; ++i)
#pragma unroll
        for (int j = 0; j < NFR; ++j)
          acc[i][j] = __builtin_amdgcn_mfma_f32_16x16x32_bf16(af[i], bfv[j], acc[i][j], 0, 0, 0);
    }
    __syncthreads();   // all reads of the buffer done before next stage (WAR)
  }

  // epilogue: C/D layout col = lane&15, row = (lane>>4)*4 + reg  (m89-verified)
#pragma unroll
  for (int i = 0; i < 4; ++i) {
#pragma unroll
    for (int j = 0; j < NFR; ++j) {
#pragma unroll
      for (int r = 0; r < 4; ++r) {
        int m = rb * 128 + wr * 64 + i * 16 + lg * 4 + r;
        int n = cb * BN + wc * (BN / 2) + j * 16 + lq;
        float v = acc[i][j][r];
        if (EPI == 0) {
          int which = n >> 10;
          int h = (n >> 6) & 15;
          int d = n & 63;
          int b = m >> 11;
          int tt = m & 2047;
          int bh = b * H_NUM + h;
          if (which == 0) {
            // fold softmax scale AND log2(e) so attention uses exp2 directly
            q_ws[((size_t)bh * T_SEQ + tt) * H_D + d] = f2bf(v * 0.18033688f);
          } else if (which == 1) {
            k_ws[((size_t)bh * T_SEQ + tt) * H_D + d] = f2bf(v);
          } else {
            // V transposed [BH,D,T'] with per-64-tile k-permutation matching
            // the swapped-QK^T in-register P layout (bijective bit shuffle)
            int k0 = tt & 63;
            int tp = (tt & ~63) | ((k0 & 12) << 1) | ((k0 & 48) >> 3) | (k0 & 1) | ((k0 & 2) << 4);
            v_ws[((size_t)bh * H_D + d) * T_SEQ + tp] = f2bf(v);
          }
        } else {
          outf[(size_t)m * 1024 + n] = v;
        }
      }
    }
  }
}

// ---------------------------------------------------------------- flash attention
// (unchanged -- counted-vmcnt 3-buffer pipeline, swapped QK^T in-lane softmax)
__global__ __launch_bounds__(256, 2) void attn_kernel(
    const unsigned short* __restrict__ qw,
    const unsigned short* __restrict__ kw,
    const unsigned short* __restrict__ vtw,
    unsigned short* __restrict__ yw) {
  __shared__ unsigned short kv_lds[3][8192];   // 3 bufs x (K 4096 | V 4096 shorts) = 48KB

  const int bid = blockIdx.x;
  const int bh = (bid & 7) * 8 + ((bid >> 3) & 7);
  const int qblk = bid >> 6;                    // 0..7, 256 rows each

  const int t = threadIdx.x;
  const int w = t >> 6, l = t & 63;
  const int lq = l & 15, lg = l >> 4;
  const int qbase = qblk * 256 + w * 64;
  const size_t head_off = (size_t)bh * T_SEQ * H_D;

  bf16x8 aq[4][2];
#pragma unroll
  for (int qg = 0; qg < 4; ++qg)
#pragma unroll
    for (int kk = 0; kk < 2; ++kk)
      aq[qg][kk] = *reinterpret_cast<const bf16x8*>(
          qw + head_off + (size_t)(qbase + qg * 16 + lq) * H_D + kk * 32 + lg * 8);

  const unsigned short* sbase[4];
  int sstep[4];
#pragma unroll
  for (int i = 0; i < 4; ++i) {
    int c = w * 64 + l + 256 * i;
    if (c < 512) {
      int row = c >> 3, sl = (c & 7) ^ (row & 7);
      sbase[i] = kw + head_off + row * H_D + sl * 8;
      sstep[i] = 64 * H_D;
    } else {
      int c2 = c - 512;
      int row = c2 >> 3, sl = (c2 & 7) ^ (row & 7);
      sbase[i] = vtw + head_off + (size_t)row * T_SEQ + sl * 8;
      sstep[i] = 64;
    }
  }

  unsigned short* bA = &kv_lds[0][0];
  unsigned short* bB = &kv_lds[1][0];
  unsigned short* bC = &kv_lds[2][0];

#define STAGE(KV, DST)                                                              \
  { _Pragma("unroll")                                                               \
    for (int i = 0; i < 4; ++i)                                                     \
      gload_lds16(sbase[i] + (size_t)(KV) * sstep[i], (DST) + (w * 64 + 256 * i) * 8); }

  STAGE(0, bA)
  STAGE(1, bB)

  f32x4 y[4][4] = {};
  float lrow[4] = {0.f, 0.f, 0.f, 0.f};
  union pa_t { bf16x8 v; unsigned int u[4]; };

  for (int kv = 0; kv < T_SEQ / 64; ++kv) {
    if (kv == T_SEQ / 64 - 1) {
      asm volatile("s_waitcnt vmcnt(0)" ::: "memory");
    } else {
      asm volatile("s_waitcnt vmcnt(4)" ::: "memory");
    }
    __builtin_amdgcn_s_barrier();

    bf16x8 kf[8], vf[8];
#pragma unroll
    for (int f = 0; f < 8; ++f) {
      int row = (f >> 1) * 16 + lq;
      int sl = ((f & 1) * 4 + lg) ^ (lq & 7);
      kf[f] = *reinterpret_cast<const bf16x8*>(bA + row * 64 + sl * 8);
    }
#pragma unroll
    for (int db = 0; db < 4; ++db)
#pragma unroll
      for (int ks = 0; ks < 2; ++ks) {
        int row = db * 16 + lq;
        int sl = (ks * 4 + lg) ^ (lq & 7);
        vf[db * 2 + ks] = *reinterpret_cast<const bf16x8*>(bA + 4096 + row * 64 + sl * 8);
      }

    pa_t pa0[4], pa1[4];
#pragma unroll
    for (int qg = 0; qg < 4; ++qg) {
      f32x4 s[4];
#pragma unroll
      for (int tt = 0; tt < 4; ++tt) {
        f32x4 z = {0.f, 0.f, 0.f, 0.f};
        s[tt] = __builtin_amdgcn_mfma_f32_16x16x32_bf16(kf[tt * 2], aq[qg][0], z, 0, 0, 0);
        s[tt] = __builtin_amdgcn_mfma_f32_16x16x32_bf16(kf[tt * 2 + 1], aq[qg][1], s[tt], 0, 0, 0);
      }
      float acc_e = 0.f;
#pragma unroll
      for (int tt = 0; tt < 4; ++tt) {
        float e0 = __builtin_amdgcn_exp2f(s[tt][0]);
        float e1 = __builtin_amdgcn_exp2f(s[tt][1]);
        float e2 = __builtin_amdgcn_exp2f(s[tt][2]);
        float e3 = __builtin_amdgcn_exp2f(s[tt][3]);
        pa0[qg].u[tt] = pack_hi(e0, e1);
        pa1[qg].u[tt] = pack_hi(e2, e3);
        acc_e += (e0 + e1) + (e2 + e3);
      }
      lrow[qg] += acc_e;
    }

#pragma unroll
    for (int qg = 0; qg < 4; ++qg)
#pragma unroll
      for (int db = 0; db < 4; ++db) {
        y[qg][db] = __builtin_amdgcn_mfma_f32_16x16x32_bf16(pa0[qg].v, vf[db * 2], y[qg][db], 0, 0, 0);
        y[qg][db] = __builtin_amdgcn_mfma_f32_16x16x32_bf16(pa1[qg].v, vf[db * 2 + 1], y[qg][db], 0, 0, 0);
      }

    if (kv + 2 < T_SEQ / 64) STAGE(kv + 2, bC)

    unsigned short* tmp = bA; bA = bB; bB = bC; bC = tmp;
  }
#undef STAGE

  const int b = bh >> 4, h = bh & 15;
#pragma unroll
  for (int qg = 0; qg < 4; ++qg) {
    float sm = lrow[qg];
    sm += __shfl_xor(sm, 16);
    sm += __shfl_xor(sm, 32);
    float inv = 1.0f / sm;
#pragma unroll
    for (int r = 0; r < 4; ++r) {
      float iv = __shfl(inv, lg * 4 + r);
      int row = qbase + qg * 16 + lg * 4 + r;
#pragma unroll
      for (int db = 0; db < 4; ++db) {
        int d = db * 16 + lq;
        yw[((size_t)(b * T_SEQ + row)) * C_DIM + h * 64 + d] = f2bf(y[qg][db][r] * iv);
      }
    }
  }
}

// ---------------------------------------------------------------- launch
extern "C" void kernel_launch(void* const* d_in, const int* in_sizes, int n_in,
                              void* d_out, int out_size, void* d_ws, size_t ws_size,
                              hipStream_t stream) {
  (void)in_sizes; (void)n_in; (void)out_size; (void)ws_size;
  const float* x      = (const float*)d_in[0];
  const float* w_attn = (const float*)d_in[1];
  const float* w_proj = (const float*)d_in[2];
  float* out = (float*)d_out;

  unsigned short* ws = (unsigned short*)d_ws;
  const size_t XB = (size_t)M_ROWS * C_DIM;          // 8,388,608
  unsigned short* xb  = ws;                          // x bf16 [8192,1024]; reused as y after attn
  unsigned short* wab = xb + XB;                     // w_attn bf16 [3072,1024]
  unsigned short* wpb = wab + (size_t)3072 * 1024;   // w_proj bf16 [1024,1024]
  unsigned short* qws = wpb + (size_t)1024 * 1024;   // q [BH,T,D] (pre-scaled by 0.125*log2e)
  unsigned short* kws = qws + XB;                    // k [BH,T,D]
  unsigned short* vws = kws + XB;                    // v^T [BH,D,T'] k-permuted
  unsigned short* yws = xb;                          // attention output [B,T,C] (xb dead by then)

  cast_all_kernel<<<3145728 / 256, 256, 0, stream>>>(x, w_attn, w_proj, xb, wab, wpb);

  gemm_bt_kernel<0><<<3072, 256, 0, stream>>>(xb, wab, qws, kws, vws, nullptr);
  attn_kernel<<<512, 256, 0, stream>>>(qws, kws, vws, yws);
  gemm_bt_kernel<1><<<512, 256, 0, stream>>>(yws, wpb, nullptr, nullptr, nullptr, out);
}

// Round 13
// 177.673 us; speedup vs baseline: 1.1829x; 1.1829x over previous
//
#include <hip/hip_runtime.h>

// Problem constants
#define T_SEQ 2048
#define C_DIM 1024
#define H_NUM 16
#define H_D   64
#define B_NUM 4
#define M_ROWS 8192   // B*T

typedef __attribute__((ext_vector_type(4))) float f32x4;
typedef __attribute__((ext_vector_type(8))) short bf16x8;   // 8 bf16 = 4 VGPRs (per guide §3)

__device__ __forceinline__ unsigned short f2bf(float f) {
  union { float f; unsigned int u; } a;
  a.f = f;
  unsigned int u = a.u;
  u += 0x7fffu + ((u >> 16) & 1u);   // RNE
  return (unsigned short)(u >> 16);
}

__device__ __forceinline__ unsigned int fbits(float f) {
  union { float f; unsigned int u; } a; a.f = f; return a.u;
}

// pack the high halves (bf16-truncate) of two f32 into one u32: {hi(b), hi(a)}
__device__ __forceinline__ unsigned int pack_hi(float a, float b) {
#if __has_builtin(__builtin_amdgcn_perm)
  return __builtin_amdgcn_perm(fbits(b), fbits(a), 0x07060302u);  // 1 VALU op
#else
  return (fbits(b) & 0xffff0000u) | (fbits(a) >> 16);
#endif
}

// async global->LDS, 16B per lane; LDS dest = wave-uniform base + lane*16
__device__ __forceinline__ void gload_lds16(const unsigned short* g, unsigned short* l) {
  __builtin_amdgcn_global_load_lds(
      (const __attribute__((address_space(1))) unsigned int*)g,
      (__attribute__((address_space(3))) unsigned int*)l, 16, 0, 0);
}

// ---------------------------------------------------------------- fused cast fp32 -> bf16
__global__ __launch_bounds__(256) void cast_all_kernel(const float* __restrict__ x,
                                                       const float* __restrict__ wa,
                                                       const float* __restrict__ wp,
                                                       unsigned short* __restrict__ xb,
                                                       unsigned short* __restrict__ wab,
                                                       unsigned short* __restrict__ wpb) {
  int i = blockIdx.x * 256 + threadIdx.x;
  const float* src;
  unsigned short* dst;
  int off;
  if (i < 2097152) {           // x: 8192*1024/4
    src = x; dst = xb; off = i;
  } else if (i < 2883584) {    // w_attn: 3072*1024/4
    src = wa; dst = wab; off = i - 2097152;
  } else {                     // w_proj: 1024*1024/4
    src = wp; dst = wpb; off = i - 2883584;
  }
  float4 v = reinterpret_cast<const float4*>(src)[off];
  ushort4 o;
  o.x = f2bf(v.x); o.y = f2bf(v.y); o.z = f2bf(v.z); o.w = f2bf(v.w);
  reinterpret_cast<ushort4*>(dst)[off] = o;
}

// ---------------------------------------------------------------- GEMM  C = A * B^T
// FINAL (round 13 = round 8 verbatim; twice-measured best: 177.47 / 177.07 us).
// Session-closed law (retrodicts all 8 GEMM configs measured, r0-r12):
//   GEMM0 time = staged_bytes / min(blocks_per_CU x ~4.4 B/cy x 0.614 TB/s,
//                                   ~10.3 TB/s aggregate L2/L3 delivery cap)
//   - r4/r8 (939 MB, 4 blk): delivery-capped -> 91 us (measured 90.5-91.5)
//   - r7   (604 MB, eff 2 blk): issue-capped -> 107 us (measured 106.7)
//   - r12  (1.21 GB, 6 blk): delivery-capped -> 118 us (measured 120)
//   - r0/r3 (805 MB, 1.5-round tail): ~100 us (measured 97-101)
// Escapes all measured dead ends: bigger tiles spill the unified 128-reg
// file (r5/r6); fewer blocks go issue-bound (r7); more blocks can't raise
// the delivery cap (r12); 8-phase deep pipeline null x3 (r2/r9/r10).
// BN=96 @ 4 blk/CU, grid 64x32 = 2048 = exactly 2 resident rounds is the
// constrained optimum of staged-bytes minimization under acc<=64 f32/thread
// and grid-exactness. EPI1: BN=128 grid 512 (r7/r8 isolated, ~8-12 us
// faster than BN=64 alternative).
// EPI 0: QKV epilogue -> q*0.125*log2e, k [BH,T,D], v^T [BH,D,T'] k-permuted
// EPI 1: plain fp32 row-major [M,1024] output
template <int EPI>
__global__ __launch_bounds__(256, 4) void gemm_bt_kernel(
    const unsigned short* __restrict__ A,
    const unsigned short* __restrict__ Bw,
    unsigned short* __restrict__ q_ws,
    unsigned short* __restrict__ k_ws,
    unsigned short* __restrict__ v_ws,
    float* __restrict__ outf) {
  constexpr int BN  = (EPI == 0) ? 96 : 128;
  constexpr int NN  = (EPI == 0) ? 3072 : 1024;
  constexpr int NBC = NN / BN;           // 32 or 8
  constexpr int NFR = BN / 32;           // n-frags per wave: 3 or 4
  constexpr int BLD = BN * 8 / 256;      // B staging chunks per thread: 3 or 4
  constexpr int KK  = 1024;
  constexpr int KT  = KK / 64;           // 16
  constexpr int NWG = 64 * NBC;          // 2048 or 512 (both % 8 == 0)

  __shared__ unsigned short lds[8192 + BN * 64];   // A 16KB | B 12KB/16KB

  // T1: bijective XCD-aware swizzle (NWG % 8 == 0)
  const int bid = blockIdx.x;
  const int logical = (bid & 7) * (NWG / 8) + (bid >> 3);
  const int rb = logical / NBC, cb = logical % NBC;

  const int t = threadIdx.x;
  const int w = t >> 6, l = t & 63;
  const int wr = w >> 1, wc = w & 1;
  const int lq = l & 15, lg = l >> 4;

  const size_t a_base = (size_t)(rb * 128) * KK;
  const size_t b_base = (size_t)(cb * BN) * KK;

  // staging chunk c = t + 256*i -> (row=c>>3, slot=c&7), src slot ^= row&7
  int aRow[4], aGs[4];
#pragma unroll
  for (int i = 0; i < 4; ++i) {
    int c = t + 256 * i;
    aRow[i] = c >> 3;
    aGs[i] = (c & 7) ^ (aRow[i] & 7);
  }
  int bRow[BLD], bGs[BLD];
#pragma unroll
  for (int i = 0; i < BLD; ++i) {
    int c = t + 256 * i;
    bRow[i] = c >> 3;
    bGs[i] = (c & 7) ^ (bRow[i] & 7);
  }

  f32x4 acc[4][NFR] = {};

  for (int kt = 0; kt < KT; ++kt) {
    const int ko = kt * 64;
#pragma unroll
    for (int i = 0; i < 4; ++i)
      gload_lds16(A + a_base + (size_t)aRow[i] * KK + ko + aGs[i] * 8,
                  &lds[(t + 256 * i) * 8]);
#pragma unroll
    for (int i = 0; i < BLD; ++i)
      gload_lds16(Bw + b_base + (size_t)bRow[i] * KK + ko + bGs[i] * 8,
                  &lds[8192 + (t + 256 * i) * 8]);
    __syncthreads();   // drains vmcnt -> tile kt fully in LDS

#pragma unroll
    for (int kk = 0; kk < 2; ++kk) {
      const int sg = kk * 4 + lg;
      bf16x8 af[4], bfv[NFR];
#pragma unroll
      for (int i = 0; i < 4; ++i) {
        int R = wr * 64 + i * 16 + lq;
        af[i] = *reinterpret_cast<const bf16x8*>(&lds[(R * 8 + (sg ^ (R & 7))) * 8]);
      }
#pragma unroll
      for (int j = 0; j < NFR; ++j) {
        int R = wc * (BN / 2) + j * 16 + lq;
        bfv[j] = *reinterpret_cast<const bf16x8*>(&lds[8192 + (R * 8 + (sg ^ (R & 7))) * 8]);
      }
#pragma unroll
      for (int i = 0; i < 4; ++i)
#pragma unroll
        for (int j = 0; j < NFR; ++j)
          acc[i][j] = __builtin_amdgcn_mfma_f32_16x16x32_bf16(af[i], bfv[j], acc[i][j], 0, 0, 0);
    }
    __syncthreads();   // all reads of the buffer done before next stage (WAR)
  }

  // epilogue: C/D layout col = lane&15, row = (lane>>4)*4 + reg  (m89-verified)
#pragma unroll
  for (int i = 0; i < 4; ++i) {
#pragma unroll
    for (int j = 0; j < NFR; ++j) {
#pragma unroll
      for (int r = 0; r < 4; ++r) {
        int m = rb * 128 + wr * 64 + i * 16 + lg * 4 + r;
        int n = cb * BN + wc * (BN / 2) + j * 16 + lq;
        float v = acc[i][j][r];
        if (EPI == 0) {
          int which = n >> 10;
          int h = (n >> 6) & 15;
          int d = n & 63;
          int b = m >> 11;
          int tt = m & 2047;
          int bh = b * H_NUM + h;
          if (which == 0) {
            // fold softmax scale AND log2(e) so attention uses exp2 directly
            q_ws[((size_t)bh * T_SEQ + tt) * H_D + d] = f2bf(v * 0.18033688f);
          } else if (which == 1) {
            k_ws[((size_t)bh * T_SEQ + tt) * H_D + d] = f2bf(v);
          } else {
            // V transposed [BH,D,T'] with per-64-tile k-permutation matching
            // the swapped-QK^T in-register P layout (bijective bit shuffle)
            int k0 = tt & 63;
            int tp = (tt & ~63) | ((k0 & 12) << 1) | ((k0 & 48) >> 3) | (k0 & 1) | ((k0 & 2) << 4);
            v_ws[((size_t)bh * H_D + d) * T_SEQ + tp] = f2bf(v);
          }
        } else {
          outf[(size_t)m * 1024 + n] = v;
        }
      }
    }
  }
}

// ---------------------------------------------------------------- flash attention
// (unchanged -- counted-vmcnt 3-buffer pipeline, swapped QK^T in-lane softmax)
__global__ __launch_bounds__(256, 2) void attn_kernel(
    const unsigned short* __restrict__ qw,
    const unsigned short* __restrict__ kw,
    const unsigned short* __restrict__ vtw,
    unsigned short* __restrict__ yw) {
  __shared__ unsigned short kv_lds[3][8192];   // 3 bufs x (K 4096 | V 4096 shorts) = 48KB

  const int bid = blockIdx.x;
  const int bh = (bid & 7) * 8 + ((bid >> 3) & 7);
  const int qblk = bid >> 6;                    // 0..7, 256 rows each

  const int t = threadIdx.x;
  const int w = t >> 6, l = t & 63;
  const int lq = l & 15, lg = l >> 4;
  const int qbase = qblk * 256 + w * 64;
  const size_t head_off = (size_t)bh * T_SEQ * H_D;

  bf16x8 aq[4][2];
#pragma unroll
  for (int qg = 0; qg < 4; ++qg)
#pragma unroll
    for (int kk = 0; kk < 2; ++kk)
      aq[qg][kk] = *reinterpret_cast<const bf16x8*>(
          qw + head_off + (size_t)(qbase + qg * 16 + lq) * H_D + kk * 32 + lg * 8);

  const unsigned short* sbase[4];
  int sstep[4];
#pragma unroll
  for (int i = 0; i < 4; ++i) {
    int c = w * 64 + l + 256 * i;
    if (c < 512) {
      int row = c >> 3, sl = (c & 7) ^ (row & 7);
      sbase[i] = kw + head_off + row * H_D + sl * 8;
      sstep[i] = 64 * H_D;
    } else {
      int c2 = c - 512;
      int row = c2 >> 3, sl = (c2 & 7) ^ (row & 7);
      sbase[i] = vtw + head_off + (size_t)row * T_SEQ + sl * 8;
      sstep[i] = 64;
    }
  }

  unsigned short* bA = &kv_lds[0][0];
  unsigned short* bB = &kv_lds[1][0];
  unsigned short* bC = &kv_lds[2][0];

#define STAGE(KV, DST)                                                              \
  { _Pragma("unroll")                                                               \
    for (int i = 0; i < 4; ++i)                                                     \
      gload_lds16(sbase[i] + (size_t)(KV) * sstep[i], (DST) + (w * 64 + 256 * i) * 8); }

  STAGE(0, bA)
  STAGE(1, bB)

  f32x4 y[4][4] = {};
  float lrow[4] = {0.f, 0.f, 0.f, 0.f};
  union pa_t { bf16x8 v; unsigned int u[4]; };

  for (int kv = 0; kv < T_SEQ / 64; ++kv) {
    if (kv == T_SEQ / 64 - 1) {
      asm volatile("s_waitcnt vmcnt(0)" ::: "memory");
    } else {
      asm volatile("s_waitcnt vmcnt(4)" ::: "memory");
    }
    __builtin_amdgcn_s_barrier();

    bf16x8 kf[8], vf[8];
#pragma unroll
    for (int f = 0; f < 8; ++f) {
      int row = (f >> 1) * 16 + lq;
      int sl = ((f & 1) * 4 + lg) ^ (lq & 7);
      kf[f] = *reinterpret_cast<const bf16x8*>(bA + row * 64 + sl * 8);
    }
#pragma unroll
    for (int db = 0; db < 4; ++db)
#pragma unroll
      for (int ks = 0; ks < 2; ++ks) {
        int row = db * 16 + lq;
        int sl = (ks * 4 + lg) ^ (lq & 7);
        vf[db * 2 + ks] = *reinterpret_cast<const bf16x8*>(bA + 4096 + row * 64 + sl * 8);
      }

    pa_t pa0[4], pa1[4];
#pragma unroll
    for (int qg = 0; qg < 4; ++qg) {
      f32x4 s[4];
#pragma unroll
      for (int tt = 0; tt < 4; ++tt) {
        f32x4 z = {0.f, 0.f, 0.f, 0.f};
        s[tt] = __builtin_amdgcn_mfma_f32_16x16x32_bf16(kf[tt * 2], aq[qg][0], z, 0, 0, 0);
        s[tt] = __builtin_amdgcn_mfma_f32_16x16x32_bf16(kf[tt * 2 + 1], aq[qg][1], s[tt], 0, 0, 0);
      }
      float acc_e = 0.f;
#pragma unroll
      for (int tt = 0; tt < 4; ++tt) {
        float e0 = __builtin_amdgcn_exp2f(s[tt][0]);
        float e1 = __builtin_amdgcn_exp2f(s[tt][1]);
        float e2 = __builtin_amdgcn_exp2f(s[tt][2]);
        float e3 = __builtin_amdgcn_exp2f(s[tt][3]);
        pa0[qg].u[tt] = pack_hi(e0, e1);
        pa1[qg].u[tt] = pack_hi(e2, e3);
        acc_e += (e0 + e1) + (e2 + e3);
      }
      lrow[qg] += acc_e;
    }

#pragma unroll
    for (int qg = 0; qg < 4; ++qg)
#pragma unroll
      for (int db = 0; db < 4; ++db) {
        y[qg][db] = __builtin_amdgcn_mfma_f32_16x16x32_bf16(pa0[qg].v, vf[db * 2], y[qg][db], 0, 0, 0);
        y[qg][db] = __builtin_amdgcn_mfma_f32_16x16x32_bf16(pa1[qg].v, vf[db * 2 + 1], y[qg][db], 0, 0, 0);
      }

    if (kv + 2 < T_SEQ / 64) STAGE(kv + 2, bC)

    unsigned short* tmp = bA; bA = bB; bB = bC; bC = tmp;
  }
#undef STAGE

  const int b = bh >> 4, h = bh & 15;
#pragma unroll
  for (int qg = 0; qg < 4; ++qg) {
    float sm = lrow[qg];
    sm += __shfl_xor(sm, 16);
    sm += __shfl_xor(sm, 32);
    float inv = 1.0f / sm;
#pragma unroll
    for (int r = 0; r < 4; ++r) {
      float iv = __shfl(inv, lg * 4 + r);
      int row = qbase + qg * 16 + lg * 4 + r;
#pragma unroll
      for (int db = 0; db < 4; ++db) {
        int d = db * 16 + lq;
        yw[((size_t)(b * T_SEQ + row)) * C_DIM + h * 64 + d] = f2bf(y[qg][db][r] * iv);
      }
    }
  }
}

// ---------------------------------------------------------------- launch
extern "C" void kernel_launch(void* const* d_in, const int* in_sizes, int n_in,
                              void* d_out, int out_size, void* d_ws, size_t ws_size,
                              hipStream_t stream) {
  (void)in_sizes; (void)n_in; (void)out_size; (void)ws_size;
  const float* x      = (const float*)d_in[0];
  const float* w_attn = (const float*)d_in[1];
  const float* w_proj = (const float*)d_in[2];
  float* out = (float*)d_out;

  unsigned short* ws = (unsigned short*)d_ws;
  const size_t XB = (size_t)M_ROWS * C_DIM;          // 8,388,608
  unsigned short* xb  = ws;                          // x bf16 [8192,1024]; reused as y after attn
  unsigned short* wab = xb + XB;                     // w_attn bf16 [3072,1024]
  unsigned short* wpb = wab + (size_t)3072 * 1024;   // w_proj bf16 [1024,1024]
  unsigned short* qws = wpb + (size_t)1024 * 1024;   // q [BH,T,D] (pre-scaled by 0.125*log2e)
  unsigned short* kws = qws + XB;                    // k [BH,T,D]
  unsigned short* vws = kws + XB;                    // v^T [BH,D,T'] k-permuted
  unsigned short* yws = xb;                          // attention output [B,T,C] (xb dead by then)

  cast_all_kernel<<<3145728 / 256, 256, 0, stream>>>(x, w_attn, w_proj, xb, wab, wpb);

  gemm_bt_kernel<0><<<2048, 256, 0, stream>>>(xb, wab, qws, kws, vws, nullptr);
  attn_kernel<<<512, 256, 0, stream>>>(qws, kws, vws, yws);
  gemm_bt_kernel<1><<<512, 256, 0, stream>>>(yws, wpb, nullptr, nullptr, nullptr, out);
}